// Round 1
// baseline (909.683 us; speedup 1.0000x reference)
//
#include <hip/hip_runtime.h>

#define OUT_FEAT 11008
#define IN_FEAT  4096
#define HAD      128

typedef __attribute__((ext_vector_type(8))) _Float16 f16x8;
typedef __attribute__((ext_vector_type(4))) float    f32x4;

// ---------------------------------------------------------------- stage 16B/lane
__device__ __forceinline__ void lds_load16(const _Float16* g, _Float16* l) {
    __builtin_amdgcn_global_load_lds(
        (const __attribute__((address_space(1))) void*)g,
        (__attribute__((address_space(3))) void*)l, 16, 0, 0);
}

// ---------------------------------------------------------------- kernel 1: Bt[n][k] = (f16)R_left[k][n]
__global__ void k_transpose_convert(const float* __restrict__ Rl, _Float16* __restrict__ Bt) {
    __shared__ float tile[64][65];
    int n0 = blockIdx.x * 64;
    int k0 = blockIdx.y * 64;
    int t  = threadIdx.x;
    int tn = t & 63;
    int tr = t >> 6;
#pragma unroll
    for (int r = 0; r < 16; ++r) {
        int kk = r * 4 + tr;
        tile[kk][tn] = Rl[(size_t)(k0 + kk) * IN_FEAT + n0 + tn];
    }
    __syncthreads();
#pragma unroll
    for (int r = 0; r < 16; ++r) {
        int nn = r * 4 + tr;
        Bt[(size_t)(n0 + nn) * IN_FEAT + k0 + tn] = (_Float16)tile[tn][nn];
    }
}

// ---------------------------------------------------------------- kernel 2: W = Rblock @ inp  (fp32 compute, fp16 out)
// W[b*128 + j, i] = sum_k Rr[k, j] * inp[b*128 + k, i]
__global__ __launch_bounds__(256, 1) void k_rotate(const float* __restrict__ inp,
                                                   const float* __restrict__ Rr,
                                                   _Float16* __restrict__ W) {
    __shared__ float sR[HAD * HAD];   // [k][j]
    __shared__ float sX[HAD * 128];   // [k][ii]
    int i0 = blockIdx.x * 128;
    int b  = blockIdx.y;
    int t  = threadIdx.x;

    for (int r = 0; r < 64; ++r) {
        int idx = r * 256 + t;
        sR[idx] = Rr[idx];
    }
    const float* xsrc = inp + (size_t)b * HAD * IN_FEAT + i0;
    for (int r = 0; r < 64; ++r) {
        int idx = r * 256 + t;
        int k = idx >> 7, ii = idx & 127;
        sX[idx] = xsrc[(size_t)k * IN_FEAT + ii];
    }
    __syncthreads();

    int tx = t & 15, ty = t >> 4;
    int j0 = ty * 8, ii0 = tx * 8;
    float acc[8][8];
#pragma unroll
    for (int a = 0; a < 8; ++a)
#pragma unroll
        for (int c = 0; c < 8; ++c) acc[a][c] = 0.f;

    for (int k = 0; k < 128; ++k) {
        float4 ra = *(const float4*)&sR[k * 128 + j0];
        float4 rb = *(const float4*)&sR[k * 128 + j0 + 4];
        float4 xa = *(const float4*)&sX[k * 128 + ii0];
        float4 xb = *(const float4*)&sX[k * 128 + ii0 + 4];
        float rv[8] = {ra.x, ra.y, ra.z, ra.w, rb.x, rb.y, rb.z, rb.w};
        float xv[8] = {xa.x, xa.y, xa.z, xa.w, xb.x, xb.y, xb.z, xb.w};
#pragma unroll
        for (int jj = 0; jj < 8; ++jj)
#pragma unroll
            for (int ii = 0; ii < 8; ++ii)
                acc[jj][ii] = fmaf(rv[jj], xv[ii], acc[jj][ii]);
    }

#pragma unroll
    for (int jj = 0; jj < 8; ++jj) {
        f16x8 v;
#pragma unroll
        for (int ii = 0; ii < 8; ++ii) v[ii] = (_Float16)acc[jj][ii];
        *(f16x8*)&W[(size_t)(b * HAD + j0 + jj) * IN_FEAT + i0 + ii0] = v;
    }
}

// ---------------------------------------------------------------- kernel 3: Z = W @ R_left  (fp16 MFMA, fp32 out) + absmax
#define BM 128
#define BN 128
#define BK 32

__global__ __launch_bounds__(256, 2) void k_gemm(const _Float16* __restrict__ A,  // W [11008][4096]
                                                 const _Float16* __restrict__ B,  // Bt [4096 n][4096 k]
                                                 float* __restrict__ C,
                                                 unsigned* __restrict__ absmax) {
    __shared__ _Float16 sA[2][BM * BK];
    __shared__ _Float16 sB[2][BN * BK];

    int m0 = blockIdx.x * BM;
    int n0 = blockIdx.y * BN;
    int t    = threadIdx.x;
    int lane = t & 63;
    int w    = t >> 6;
    int wr   = w >> 1, wc = w & 1;

    // staging source: thread t covers row t/4 (+64 for 2nd instr), cols (t%4)*8..+7
    const _Float16* a0 = A + (size_t)(m0 + (t >> 2)) * IN_FEAT + (t & 3) * 8;
    const _Float16* b0 = B + (size_t)(n0 + (t >> 2)) * IN_FEAT + (t & 3) * 8;

    f32x4 acc[4][4] = {};

    auto stage = [&](int buf, int kt) {
        const _Float16* as = a0 + kt * BK;
        const _Float16* bs = b0 + kt * BK;
        _Float16* la = &sA[buf][w * 512];
        _Float16* lb = &sB[buf][w * 512];
        lds_load16(as, la);
        lds_load16(as + (size_t)64 * IN_FEAT, la + 2048);
        lds_load16(bs, lb);
        lds_load16(bs + (size_t)64 * IN_FEAT, lb + 2048);
    };

    stage(0, 0);
    const int NT = IN_FEAT / BK;  // 128
    int cur = 0;
    for (int kt = 0; kt < NT; ++kt) {
        __syncthreads();
        if (kt + 1 < NT) stage(cur ^ 1, kt + 1);
        const _Float16* pa = &sA[cur][(wr * 64 + (lane & 15)) * BK + (lane >> 4) * 8];
        const _Float16* pb = &sB[cur][(wc * 64 + (lane & 15)) * BK + (lane >> 4) * 8];
        f16x8 av[4], bv[4];
#pragma unroll
        for (int i = 0; i < 4; ++i) {
            av[i] = *(const f16x8*)(pa + i * 16 * BK);
            bv[i] = *(const f16x8*)(pb + i * 16 * BK);
        }
#pragma unroll
        for (int mi = 0; mi < 4; ++mi)
#pragma unroll
            for (int ni = 0; ni < 4; ++ni)
                acc[mi][ni] = __builtin_amdgcn_mfma_f32_16x16x32_f16(av[mi], bv[ni], acc[mi][ni], 0, 0, 0);
        cur ^= 1;
    }

    // absmax reduction (all values >= 0 -> uint bit compare valid)
    float mx = 0.f;
#pragma unroll
    for (int mi = 0; mi < 4; ++mi)
#pragma unroll
        for (int ni = 0; ni < 4; ++ni)
#pragma unroll
            for (int r = 0; r < 4; ++r) mx = fmaxf(mx, fabsf(acc[mi][ni][r]));
#pragma unroll
    for (int off = 32; off; off >>= 1) mx = fmaxf(mx, __shfl_xor(mx, off));
    if (lane == 0) atomicMax(absmax, __float_as_uint(mx));

    // C write: row = (lane>>4)*4 + r, col = lane&15 within each 16x16 fragment
#pragma unroll
    for (int mi = 0; mi < 4; ++mi) {
        int row_base = m0 + wr * 64 + mi * 16 + (lane >> 4) * 4;
#pragma unroll
        for (int ni = 0; ni < 4; ++ni) {
            int col = n0 + wc * 64 + ni * 16 + (lane & 15);
#pragma unroll
            for (int r = 0; r < 4; ++r)
                C[(size_t)(row_base + r) * IN_FEAT + col] = acc[mi][ni][r];
        }
    }
}

// ---------------------------------------------------------------- kernel 4: in-place fake-quant
__global__ void k_quant(float* __restrict__ C, const unsigned* __restrict__ absmax, int n4) {
    int i = blockIdx.x * blockDim.x + threadIdx.x;
    if (i >= n4) return;
    float amax  = __uint_as_float(*absmax);
    float scale = fmaxf(amax / 127.0f, 1.17549435e-38f);
    float4 v = ((const float4*)C)[i];
    float4 o;
    o.x = fminf(127.f, fmaxf(-127.f, rintf(v.x / scale))) * scale;
    o.y = fminf(127.f, fmaxf(-127.f, rintf(v.y / scale))) * scale;
    o.z = fminf(127.f, fmaxf(-127.f, rintf(v.z / scale))) * scale;
    o.w = fminf(127.f, fmaxf(-127.f, rintf(v.w / scale))) * scale;
    ((float4*)C)[i] = o;
}

// ---------------------------------------------------------------- launch
extern "C" void kernel_launch(void* const* d_in, const int* in_sizes, int n_in,
                              void* d_out, int out_size, void* d_ws, size_t ws_size,
                              hipStream_t stream) {
    const float* inp = (const float*)d_in[0];
    const float* Rl  = (const float*)d_in[1];
    const float* Rr  = (const float*)d_in[2];
    float* out = (float*)d_out;

    char* ws = (char*)d_ws;
    const size_t W_BYTES  = (size_t)OUT_FEAT * IN_FEAT * 2;  // 90,177,536
    const size_t BT_BYTES = (size_t)IN_FEAT * IN_FEAT * 2;   // 33,554,432
    _Float16* Wh   = (_Float16*)ws;
    _Float16* Bt   = (_Float16*)(ws + W_BYTES);
    unsigned* amax = (unsigned*)(ws + W_BYTES + BT_BYTES);

    hipMemsetAsync(amax, 0, 4, stream);
    k_transpose_convert<<<dim3(IN_FEAT / 64, IN_FEAT / 64), 256, 0, stream>>>(Rl, Bt);
    k_rotate<<<dim3(IN_FEAT / 128, OUT_FEAT / HAD), 256, 0, stream>>>(inp, Rr, Wh);
    k_gemm<<<dim3(OUT_FEAT / BM, IN_FEAT / BN), 256, 0, stream>>>(Wh, Bt, out, amax);
    int n4 = OUT_FEAT * IN_FEAT / 4;
    k_quant<<<(n4 + 255) / 256, 256, 0, stream>>>(out, amax, n4);
}

// Round 2
// 699.299 us; speedup vs baseline: 1.3009x; 1.3009x over previous
//
#include <hip/hip_runtime.h>

#define OUT_FEAT 11008
#define IN_FEAT  4096
#define HAD      128

typedef __attribute__((ext_vector_type(8))) _Float16 f16x8;
typedef __attribute__((ext_vector_type(4))) float    f32x4;

// ---------------------------------------------------------------- stage 16B/lane
__device__ __forceinline__ void lds_load16(const _Float16* g, _Float16* l) {
    __builtin_amdgcn_global_load_lds(
        (const __attribute__((address_space(1))) void*)g,
        (__attribute__((address_space(3))) void*)l, 16, 0, 0);
}

// ---------------------------------------------------------------- kernel 1: Bt[n][k] = (f16)R_left[k][n]
__global__ void k_transpose_convert(const float* __restrict__ Rl, _Float16* __restrict__ Bt) {
    __shared__ float tile[64][65];
    int n0 = blockIdx.x * 64;
    int k0 = blockIdx.y * 64;
    int t  = threadIdx.x;
    int tn = t & 63;
    int tr = t >> 6;
#pragma unroll
    for (int r = 0; r < 16; ++r) {
        int kk = r * 4 + tr;
        tile[kk][tn] = Rl[(size_t)(k0 + kk) * IN_FEAT + n0 + tn];
    }
    __syncthreads();
#pragma unroll
    for (int r = 0; r < 16; ++r) {
        int nn = r * 4 + tr;
        Bt[(size_t)(n0 + nn) * IN_FEAT + k0 + tn] = (_Float16)tile[tn][nn];
    }
}

// ---------------------------------------------------------------- kernel 2: W = Rblock @ inp  (fp32 compute, fp16 out)
__global__ __launch_bounds__(256, 1) void k_rotate(const float* __restrict__ inp,
                                                   const float* __restrict__ Rr,
                                                   _Float16* __restrict__ W) {
    __shared__ float sR[HAD * HAD];   // [k][j]
    __shared__ float sX[HAD * 128];   // [k][ii]
    int i0 = blockIdx.x * 128;
    int b  = blockIdx.y;
    int t  = threadIdx.x;

    for (int r = 0; r < 64; ++r) {
        int idx = r * 256 + t;
        sR[idx] = Rr[idx];
    }
    const float* xsrc = inp + (size_t)b * HAD * IN_FEAT + i0;
    for (int r = 0; r < 64; ++r) {
        int idx = r * 256 + t;
        int k = idx >> 7, ii = idx & 127;
        sX[idx] = xsrc[(size_t)k * IN_FEAT + ii];
    }
    __syncthreads();

    int tx = t & 15, ty = t >> 4;
    int j0 = ty * 8, ii0 = tx * 8;
    float acc[8][8];
#pragma unroll
    for (int a = 0; a < 8; ++a)
#pragma unroll
        for (int c = 0; c < 8; ++c) acc[a][c] = 0.f;

    for (int k = 0; k < 128; ++k) {
        float4 ra = *(const float4*)&sR[k * 128 + j0];
        float4 rb = *(const float4*)&sR[k * 128 + j0 + 4];
        float4 xa = *(const float4*)&sX[k * 128 + ii0];
        float4 xb = *(const float4*)&sX[k * 128 + ii0 + 4];
        float rv[8] = {ra.x, ra.y, ra.z, ra.w, rb.x, rb.y, rb.z, rb.w};
        float xv[8] = {xa.x, xa.y, xa.z, xa.w, xb.x, xb.y, xb.z, xb.w};
#pragma unroll
        for (int jj = 0; jj < 8; ++jj)
#pragma unroll
            for (int ii = 0; ii < 8; ++ii)
                acc[jj][ii] = fmaf(rv[jj], xv[ii], acc[jj][ii]);
    }

#pragma unroll
    for (int jj = 0; jj < 8; ++jj) {
        f16x8 v;
#pragma unroll
        for (int ii = 0; ii < 8; ++ii) v[ii] = (_Float16)acc[jj][ii];
        *(f16x8*)&W[(size_t)(b * HAD + j0 + jj) * IN_FEAT + i0 + ii0] = v;
    }
}

// ---------------------------------------------------------------- kernel 3: 256x256 8-phase-style GEMM
// Z = W @ Bt^T (A row-major [11008][4096] f16, B n-major [4096][4096] f16), fp32 out + absmax.
// 4-slot LDS ring (stage kt+2 while computing kt) -> counted vmcnt(4), never drain.
// LDS swizzle: chunk c8 -> c8 ^ ((row>>1)&3); inverse applied on global staging source.
#define BM 256
#define BN 256
#define BK 32
#define NT (IN_FEAT / BK)  // 128

__global__ __launch_bounds__(512, 2) void k_gemm(const _Float16* __restrict__ A,
                                                 const _Float16* __restrict__ B,
                                                 float* __restrict__ C,
                                                 unsigned* __restrict__ absmax) {
    __shared__ _Float16 sA[4][BM * BK];  // 4 x 16KB
    __shared__ _Float16 sB[4][BN * BK];  // 4 x 16KB  (128 KiB total)

    // T1: bijective XCD swizzle (gridDim.x = 688, 688 % 8 == 0)
    int obid = blockIdx.x;
    int cpx  = 688 >> 3;  // 86
    int bid  = (obid & 7) * cpx + (obid >> 3);
    int m0 = (bid >> 4) * BM;   // 43 m-tiles
    int n0 = (bid & 15) * BN;   // 16 n-tiles

    int t    = threadIdx.x;
    int lane = t & 63;
    int wid  = t >> 6;
    int wr   = wid >> 2;  // 0..1 -> M half
    int wc   = wid & 3;   // 0..3 -> N quarter

    // ---- staging: physical chunk pc gets global (row=pc>>2, col=kt*32 + ((pc&3)^((pc>>3)&3))*8)
    int pc0 = t;
    int pc1 = t + 512;
    int rowP0 = pc0 >> 2, rowP1 = pc1 >> 2;
    int csw0 = ((pc0 & 3) ^ ((pc0 >> 3) & 3)) * 8;
    int csw1 = ((pc1 & 3) ^ ((pc1 >> 3) & 3)) * 8;
    const _Float16* A0 = A + (size_t)(m0 + rowP0) * IN_FEAT + csw0;
    const _Float16* A1 = A + (size_t)(m0 + rowP1) * IN_FEAT + csw1;
    const _Float16* B0 = B + (size_t)(n0 + rowP0) * IN_FEAT + csw0;
    const _Float16* B1 = B + (size_t)(n0 + rowP1) * IN_FEAT + csw1;
    int ldsOff0 = (wid * 64) * 8;          // wave-uniform chunk base (o=0)
    int ldsOff1 = (512 + wid * 64) * 8;    // o=1

    auto stageA = [&](int s, int kt) {
        lds_load16(A0 + kt * BK, &sA[s][ldsOff0]);
        lds_load16(A1 + kt * BK, &sA[s][ldsOff1]);
    };
    auto stageB = [&](int s, int kt) {
        lds_load16(B0 + kt * BK, &sB[s][ldsOff0]);
        lds_load16(B1 + kt * BK, &sB[s][ldsOff1]);
    };

    // ---- fragment read addressing (swizzled): row r, chunk (lane>>4)^((r>>1)&3)
    int fr  = lane & 15;
    int fc8 = (((lane >> 4) ^ ((lane >> 1) & 3))) * 8;  // (r>>1)&3 == (lane>>1)&3 (bases are x16)
    int aoff0 = (wr * 128 + fr) * BK + fc8;       // phase 0 A base
    int aoff1 = (wr * 128 + 64 + fr) * BK + fc8;  // phase 1 A base
    int boff  = (wc * 64 + fr) * BK + fc8;

    f32x4 acc[8][4] = {};
    f16x8 af[4], bf[4];

    // ---- prologue: stage tiles 0,1 into slots 0,1
    stageA(0, 0); stageB(0, 0);
    stageA(1, 1); stageB(1, 1);
    asm volatile("s_waitcnt vmcnt(4)" ::: "memory");
    __builtin_amdgcn_s_barrier();

    for (int kt = 0; kt < NT; ++kt) {
        int s  = kt & 3;
        int sn = (kt + 2) & 3;
        bool st = (kt + 2) < NT;

        // ===== phase 0: read A-half(qm=0) + all B frags; stage A(kt+2) =====
        const _Float16* pa = &sA[s][aoff0];
        const _Float16* pb = &sB[s][boff];
#pragma unroll
        for (int i = 0; i < 4; ++i) bf[i] = *(const f16x8*)(pb + i * 16 * BK);
#pragma unroll
        for (int i = 0; i < 4; ++i) af[i] = *(const f16x8*)(pa + i * 16 * BK);
        if (st) stageA(sn, kt + 2);
        __builtin_amdgcn_s_barrier();
        __builtin_amdgcn_s_setprio(1);
#pragma unroll
        for (int mi = 0; mi < 4; ++mi)
#pragma unroll
            for (int ni = 0; ni < 4; ++ni)
                acc[mi][ni] = __builtin_amdgcn_mfma_f32_16x16x32_f16(af[mi], bf[ni], acc[mi][ni], 0, 0, 0);
        __builtin_amdgcn_s_setprio(0);
        __builtin_amdgcn_s_barrier();

        // ===== phase 1: read A-half(qm=1); stage B(kt+2); counted vmcnt at tile end =====
        const _Float16* pa1 = &sA[s][aoff1];
#pragma unroll
        for (int i = 0; i < 4; ++i) af[i] = *(const f16x8*)(pa1 + i * 16 * BK);
        if (st) stageB(sn, kt + 2);
        __builtin_amdgcn_s_barrier();
        __builtin_amdgcn_s_setprio(1);
#pragma unroll
        for (int mi = 0; mi < 4; ++mi)
#pragma unroll
            for (int ni = 0; ni < 4; ++ni)
                acc[4 + mi][ni] = __builtin_amdgcn_mfma_f32_16x16x32_f16(af[mi], bf[ni], acc[4 + mi][ni], 0, 0, 0);
        __builtin_amdgcn_s_setprio(0);
        if (st) asm volatile("s_waitcnt vmcnt(4)" ::: "memory");
        else    asm volatile("s_waitcnt vmcnt(0)" ::: "memory");
        __builtin_amdgcn_s_barrier();
    }

    // ---- absmax reduction
    float mx = 0.f;
#pragma unroll
    for (int mi = 0; mi < 8; ++mi)
#pragma unroll
        for (int ni = 0; ni < 4; ++ni)
#pragma unroll
            for (int r = 0; r < 4; ++r) mx = fmaxf(mx, fabsf(acc[mi][ni][r]));
#pragma unroll
    for (int off = 32; off; off >>= 1) mx = fmaxf(mx, __shfl_xor(mx, off));
    if (lane == 0) atomicMax(absmax, __float_as_uint(mx));

    // ---- C write: frag row = (lane>>4)*4 + r, col = lane&15
#pragma unroll
    for (int mi = 0; mi < 8; ++mi) {
        int row_base = m0 + wr * 128 + mi * 16 + (lane >> 4) * 4;
#pragma unroll
        for (int ni = 0; ni < 4; ++ni) {
            int col = n0 + wc * 64 + ni * 16 + (lane & 15);
#pragma unroll
            for (int r = 0; r < 4; ++r)
                C[(size_t)(row_base + r) * IN_FEAT + col] = acc[mi][ni][r];
        }
    }
}

// ---------------------------------------------------------------- kernel 4: in-place fake-quant
__global__ void k_quant(float* __restrict__ C, const unsigned* __restrict__ absmax, int n4) {
    int i = blockIdx.x * blockDim.x + threadIdx.x;
    if (i >= n4) return;
    float amax  = __uint_as_float(*absmax);
    float scale = fmaxf(amax / 127.0f, 1.17549435e-38f);
    float4 v = ((const float4*)C)[i];
    float4 o;
    o.x = fminf(127.f, fmaxf(-127.f, rintf(v.x / scale))) * scale;
    o.y = fminf(127.f, fmaxf(-127.f, rintf(v.y / scale))) * scale;
    o.z = fminf(127.f, fmaxf(-127.f, rintf(v.z / scale))) * scale;
    o.w = fminf(127.f, fmaxf(-127.f, rintf(v.w / scale))) * scale;
    ((float4*)C)[i] = o;
}

// ---------------------------------------------------------------- launch
extern "C" void kernel_launch(void* const* d_in, const int* in_sizes, int n_in,
                              void* d_out, int out_size, void* d_ws, size_t ws_size,
                              hipStream_t stream) {
    const float* inp = (const float*)d_in[0];
    const float* Rl  = (const float*)d_in[1];
    const float* Rr  = (const float*)d_in[2];
    float* out = (float*)d_out;

    char* ws = (char*)d_ws;
    const size_t W_BYTES  = (size_t)OUT_FEAT * IN_FEAT * 2;
    const size_t BT_BYTES = (size_t)IN_FEAT * IN_FEAT * 2;
    _Float16* Wh   = (_Float16*)ws;
    _Float16* Bt   = (_Float16*)(ws + W_BYTES);
    unsigned* amax = (unsigned*)(ws + W_BYTES + BT_BYTES);

    hipMemsetAsync(amax, 0, 4, stream);
    k_transpose_convert<<<dim3(IN_FEAT / 64, IN_FEAT / 64), 256, 0, stream>>>(Rl, Bt);
    k_rotate<<<dim3(IN_FEAT / 128, OUT_FEAT / HAD), 256, 0, stream>>>(inp, Rr, Wh);
    k_gemm<<<dim3((OUT_FEAT / BM) * (IN_FEAT / BN)), 512, 0, stream>>>(Wh, Bt, out, amax);
    int n4 = OUT_FEAT * IN_FEAT / 4;
    k_quant<<<(n4 + 255) / 256, 256, 0, stream>>>(out, amax, n4);
}